// Round 1
// baseline (1532.395 us; speedup 1.0000x reference)
//
#include <hip/hip_runtime.h>

#define DD 128

static inline size_t align256(size_t x){ return (x + 255) & ~(size_t)255; }

// ---------------- utility ----------------
__global__ void zero_i32_kernel(int* __restrict__ p, int n){
  int i = blockIdx.x*blockDim.x + threadIdx.x;
  if (i < n) p[i] = 0;
}

// ---------------- CSR build ----------------
__global__ void degree_kernel(const int* __restrict__ row, int E, int* __restrict__ deg){
  int e = blockIdx.x*blockDim.x + threadIdx.x;
  if (e < E) atomicAdd(&deg[row[e]], 1);
}

__global__ void chunk_sum_kernel(const int* __restrict__ deg, int N, int* __restrict__ csum){
  __shared__ int sh[256];
  int t = threadIdx.x;
  int base = blockIdx.x*1024;
  int s = 0;
  for (int i = t; i < 1024; i += 256){
    int idx = base + i;
    if (idx < N) s += deg[idx];
  }
  sh[t] = s; __syncthreads();
  for (int o = 128; o > 0; o >>= 1){
    if (t < o) sh[t] += sh[t+o];
    __syncthreads();
  }
  if (t == 0) csum[blockIdx.x] = sh[0];
}

__global__ void chunk_scan_kernel(int* __restrict__ csum, int C, int* __restrict__ total){
  if (blockIdx.x == 0 && threadIdx.x == 0){
    int run = 0;
    for (int i = 0; i < C; i++){ int v = csum[i]; csum[i] = run; run += v; }
    *total = run;
  }
}

__global__ void scan_within_kernel(const int* __restrict__ deg, int N,
                                   const int* __restrict__ csum, int* __restrict__ rowptr){
  __shared__ int a[256], b[256];
  int t = threadIdx.x;
  int base = blockIdx.x*1024 + t*4;
  int v[4]; int s = 0;
#pragma unroll
  for (int i = 0; i < 4; i++){
    int idx = base + i;
    int d = (idx < N) ? deg[idx] : 0;
    v[i] = s; s += d;
  }
  a[t] = s; __syncthreads();
  int* src = a; int* dst = b;
  for (int o = 1; o < 256; o <<= 1){
    int val = src[t];
    if (t >= o) val += src[t - o];
    dst[t] = val;
    __syncthreads();
    int* tmp = src; src = dst; dst = tmp;
  }
  int excl = (t == 0) ? 0 : src[t-1];
  int off = csum[blockIdx.x] + excl;
#pragma unroll
  for (int i = 0; i < 4; i++){
    int idx = base + i;
    if (idx < N) rowptr[idx] = off + v[i];
  }
}

__global__ void fill_kernel(const int* __restrict__ ei, const float* __restrict__ ew, int E,
                            const int* __restrict__ rowptr, int* __restrict__ cur,
                            int* __restrict__ csr_col, float* __restrict__ csr_w){
  int e = blockIdx.x*blockDim.x + threadIdx.x;
  if (e < E){
    int r = ei[e];
    int pos = rowptr[r] + atomicAdd(&cur[r], 1);
    csr_col[pos] = ei[E + e];
    csr_w[pos]   = ew[e];
  }
}

// ---------------- weight pack: wpk[l][k*DD+j] = (gc_w[l][j][k], bi_w[l][j][k]) ----------------
__global__ void pack_w_kernel(const float* __restrict__ gcw, const float* __restrict__ biw,
                              float2* __restrict__ wpk, int LYR){
  int i = blockIdx.x*blockDim.x + threadIdx.x;
  int total = LYR*DD*DD;
  if (i >= total) return;
  int l = i / (DD*DD);
  int r = i - l*(DD*DD);
  int k = r / DD;
  int j = r - k*DD;
  const float* gl = gcw + (size_t)l*DD*DD;
  const float* bl = biw + (size_t)l*DD*DD;
  wpk[i] = make_float2(gl[j*DD + k], bl[j*DD + k]);
}

// ---------------- gather: msg[n] = sum_e w*ego[col]  (one wave per node) ----------------
__global__ void gather_kernel(const int* __restrict__ rowptr, const int* __restrict__ csr_col,
                              const float* __restrict__ csr_w, const float* __restrict__ ego,
                              float* __restrict__ msg, int N){
  int wid = (int)(((size_t)blockIdx.x*blockDim.x + threadIdx.x) >> 6);
  int lane = threadIdx.x & 63;
  if (wid >= N) return;
  int beg = rowptr[wid], end = rowptr[wid+1];
  float ax = 0.f, ay = 0.f;
  for (int k = beg; k < end; k++){
    int c = csr_col[k];
    float w = csr_w[k];
    float2 v = *(const float2*)(ego + (size_t)c*DD + lane*2);
    ax = fmaf(w, v.x, ax);
    ay = fmaf(w, v.y, ay);
  }
  float2* mo = (float2*)(msg + (size_t)wid*DD);
  mo[lane] = make_float2(ax, ay);
}

// ---------------- transform: ego_out = leakyrelu(gcw@msg + gcb + biw@(ego*msg) + bib)
//                  + fused row-norm -> nscale[n] = 1/max(||ego_out[n]||, 1e-12)
__global__ __launch_bounds__(256) void transform_kernel(
    const float* __restrict__ ego_in, const float* __restrict__ msg,
    const float2* __restrict__ wpk, const float* __restrict__ gcb,
    const float* __restrict__ bib, float* __restrict__ ego_out,
    float* __restrict__ nscale, int N){
  __shared__ float2 tile[32*DD];   // (msg, ego*msg) pairs, 32 KB
  __shared__ float red[2][32];
  int t = threadIdx.x;
  int j  = t & (DD-1);
  int rg = t >> 7;                 // 0 or 1: rows rg*16 .. rg*16+15
  int r0 = blockIdx.x * 32;

  for (int i = t; i < 32*DD; i += 256){
    int r = i >> 7, c = i & (DD-1);
    int gr = r0 + r;
    float m = 0.f, e = 0.f;
    if (gr < N){ m = msg[(size_t)gr*DD + c]; e = ego_in[(size_t)gr*DD + c]; }
    tile[i] = make_float2(m, e*m);
  }
  __syncthreads();

  float acc[16];
#pragma unroll
  for (int s = 0; s < 16; s++) acc[s] = 0.f;

  const float2* wp = wpk + j;
  const float2* tp = tile + rg*16*DD;
#pragma unroll 4
  for (int k = 0; k < DD; k++){
    float2 w2 = wp[(size_t)k*DD];       // coalesced, streams 128 KB/block from L2
#pragma unroll
    for (int s = 0; s < 16; s++){
      float2 mp = tp[s*DD + k];         // wave-uniform address -> LDS broadcast
      acc[s] = fmaf(w2.x, mp.x, fmaf(w2.y, mp.y, acc[s]));
    }
  }
  float cb = gcb[j] + bib[j];
#pragma unroll
  for (int s = 0; s < 16; s++){
    float x = acc[s] + cb;
    acc[s] = (x > 0.f) ? x : 0.2f*x;    // leaky_relu(0.2)
  }
#pragma unroll
  for (int s = 0; s < 16; s++){
    int gr = r0 + rg*16 + s;
    if (gr < N) ego_out[(size_t)gr*DD + j] = acc[s];
  }
  // fused row-norm: reduce sum of squares across the 128 threads owning each row
  int half = (t >> 6) & 1;              // which 64-col half this wave covers
#pragma unroll
  for (int s = 0; s < 16; s++){
    float p2 = acc[s]*acc[s];
    for (int o = 32; o > 0; o >>= 1) p2 += __shfl_xor(p2, o, 64);
    if ((t & 63) == 0) red[half][rg*16 + s] = p2;
  }
  __syncthreads();
  if (t < 32){
    int gr = r0 + t;
    if (gr < N){
      float ss = red[0][t] + red[1][t];
      float nl = sqrtf(ss);
      nscale[gr] = 1.0f / fmaxf(nl, 1e-12f);
    }
  }
}

// ---------------- score: out[q] (+)= scale_s*scale_d * dot(feat[s], feat[d]) ----------------
__global__ void score_kernel(const int* __restrict__ eli, int Q,
                             const float* __restrict__ feat, const float* __restrict__ nscale,
                             float* __restrict__ out, int accumulate){
  int wid = (int)(((size_t)blockIdx.x*blockDim.x + threadIdx.x) >> 6);
  int lane = threadIdx.x & 63;
  if (wid >= Q) return;
  int s = eli[wid];
  int d = eli[Q + wid];
  float2 a = *(const float2*)(feat + (size_t)s*DD + lane*2);
  float2 b = *(const float2*)(feat + (size_t)d*DD + lane*2);
  float p = a.x*b.x + a.y*b.y;
  for (int o = 32; o > 0; o >>= 1) p += __shfl_xor(p, o, 64);
  if (lane == 0){
    if (nscale) p *= nscale[s]*nscale[d];
    if (accumulate) out[wid] += p;
    else            out[wid]  = p;
  }
}

extern "C" void kernel_launch(void* const* d_in, const int* in_sizes, int n_in,
                              void* d_out, int out_size, void* d_ws, size_t ws_size,
                              hipStream_t stream){
  const int*   edge_index = (const int*)d_in[0];   // (2,E)
  const int*   eli        = (const int*)d_in[1];   // (2,Q)
  const float* ew         = (const float*)d_in[2]; // (E,)
  const float* emb        = (const float*)d_in[3]; // (N,D)
  const float* gcw        = (const float*)d_in[4]; // (L,D,D)
  const float* gcb        = (const float*)d_in[5]; // (L,D)
  const float* biw        = (const float*)d_in[6]; // (L,D,D)
  const float* bib        = (const float*)d_in[7]; // (L,D)
  const int E   = in_sizes[2];
  const int Q   = in_sizes[1] / 2;
  const int N   = in_sizes[3] / DD;
  const int LYR = in_sizes[4] / (DD*DD);
  float* out = (float*)d_out;

  // workspace carve (~117 MB)
  char* base = (char*)d_ws;
  size_t off = 0;
  auto carve = [&](size_t bytes)->char*{
    char* r = base + off;
    off = align256(off + bytes);
    return r;
  };
  float*  ego    = (float*) carve((size_t)N*DD*sizeof(float));
  float*  msg    = (float*) carve((size_t)N*DD*sizeof(float));
  float2* wpk    = (float2*)carve((size_t)LYR*DD*DD*sizeof(float2));
  float*  nscale = (float*) carve((size_t)N*sizeof(float));
  int*    rowptr = (int*)   carve((size_t)(N+1)*sizeof(int));
  int*    deg    = (int*)   carve((size_t)2*N*sizeof(int));  // deg + cur contiguous
  int*    cur    = deg + N;
  int*    csum   = (int*)   carve(4096);
  int*    csr_col= (int*)   carve((size_t)E*sizeof(int));
  float*  csr_w  = (float*) carve((size_t)E*sizeof(float));
  (void)ws_size; (void)n_in; (void)out_size;

  const int C = (N + 1023)/1024;

  // CSR build
  zero_i32_kernel<<<(2*N + 255)/256, 256, 0, stream>>>(deg, 2*N);
  degree_kernel<<<(E + 255)/256, 256, 0, stream>>>(edge_index, E, deg);
  chunk_sum_kernel<<<C, 256, 0, stream>>>(deg, N, csum);
  chunk_scan_kernel<<<1, 64, 0, stream>>>(csum, C, rowptr + N);
  scan_within_kernel<<<C, 256, 0, stream>>>(deg, N, csum, rowptr);
  fill_kernel<<<(E + 255)/256, 256, 0, stream>>>(edge_index, ew, E, rowptr, cur, csr_col, csr_w);
  pack_w_kernel<<<(LYR*DD*DD + 255)/256, 256, 0, stream>>>(gcw, biw, wpk, LYR);

  // stage 0: raw emb dot
  {
    int blocks = (int)(((size_t)Q*64 + 255)/256);
    score_kernel<<<blocks, 256, 0, stream>>>(eli, Q, emb, (const float*)nullptr, out, 0);
  }

  for (int l = 0; l < LYR; l++){
    const float* src = (l == 0) ? emb : ego;
    {
      int blocks = (int)(((size_t)N*64 + 255)/256);
      gather_kernel<<<blocks, 256, 0, stream>>>(rowptr, csr_col, csr_w, src, msg, N);
    }
    transform_kernel<<<(N + 31)/32, 256, 0, stream>>>(src, msg, wpk + (size_t)l*DD*DD,
                                                      gcb + (size_t)l*DD, bib + (size_t)l*DD,
                                                      ego, nscale, N);
    {
      int blocks = (int)(((size_t)Q*64 + 255)/256);
      score_kernel<<<blocks, 256, 0, stream>>>(eli, Q, ego, nscale, out, 1);
    }
  }
}

// Round 2
// 1082.483 us; speedup vs baseline: 1.4156x; 1.4156x over previous
//
#include <hip/hip_runtime.h>

#define DD 128
#define K2 256   // concatenated K: [msg | ego*msg]

typedef short short8 __attribute__((ext_vector_type(8)));
typedef float f32x4  __attribute__((ext_vector_type(4)));

static inline size_t align256(size_t x){ return (x + 255) & ~(size_t)255; }

__device__ __forceinline__ unsigned short f2bf(float x){
  // round-to-nearest-even fp32 -> bf16
  unsigned int u = __builtin_bit_cast(unsigned int, x);
  u += 0x7fff + ((u >> 16) & 1);
  return (unsigned short)(u >> 16);
}

// ---------------- utility ----------------
__global__ void zero_i32_kernel(int* __restrict__ p, int n){
  int i = blockIdx.x*blockDim.x + threadIdx.x;
  if (i < n) p[i] = 0;
}

// ---------------- CSR build ----------------
__global__ void degree_kernel(const int* __restrict__ row, int E, int* __restrict__ deg){
  int e = blockIdx.x*blockDim.x + threadIdx.x;
  if (e < E) atomicAdd(&deg[row[e]], 1);
}

__global__ void chunk_sum_kernel(const int* __restrict__ deg, int N, int* __restrict__ csum){
  __shared__ int sh[256];
  int t = threadIdx.x;
  int base = blockIdx.x*1024;
  int s = 0;
  for (int i = t; i < 1024; i += 256){
    int idx = base + i;
    if (idx < N) s += deg[idx];
  }
  sh[t] = s; __syncthreads();
  for (int o = 128; o > 0; o >>= 1){
    if (t < o) sh[t] += sh[t+o];
    __syncthreads();
  }
  if (t == 0) csum[blockIdx.x] = sh[0];
}

__global__ void chunk_scan_kernel(int* __restrict__ csum, int C, int* __restrict__ total){
  if (blockIdx.x == 0 && threadIdx.x == 0){
    int run = 0;
    for (int i = 0; i < C; i++){ int v = csum[i]; csum[i] = run; run += v; }
    *total = run;
  }
}

__global__ void scan_within_kernel(const int* __restrict__ deg, int N,
                                   const int* __restrict__ csum, int* __restrict__ rowptr){
  __shared__ int a[256], b[256];
  int t = threadIdx.x;
  int base = blockIdx.x*1024 + t*4;
  int v[4]; int s = 0;
#pragma unroll
  for (int i = 0; i < 4; i++){
    int idx = base + i;
    int d = (idx < N) ? deg[idx] : 0;
    v[i] = s; s += d;
  }
  a[t] = s; __syncthreads();
  int* src = a; int* dst = b;
  for (int o = 1; o < 256; o <<= 1){
    int val = src[t];
    if (t >= o) val += src[t - o];
    dst[t] = val;
    __syncthreads();
    int* tmp = src; src = dst; dst = tmp;
  }
  int excl = (t == 0) ? 0 : src[t-1];
  int off = csum[blockIdx.x] + excl;
#pragma unroll
  for (int i = 0; i < 4; i++){
    int idx = base + i;
    if (idx < N) rowptr[idx] = off + v[i];
  }
}

__global__ void fill_kernel(const int* __restrict__ ei, const float* __restrict__ ew, int E,
                            const int* __restrict__ rowptr, int* __restrict__ cur,
                            int* __restrict__ csr_col, float* __restrict__ csr_w){
  int e = blockIdx.x*blockDim.x + threadIdx.x;
  if (e < E){
    int r = ei[e];
    int pos = rowptr[r] + atomicAdd(&cur[r], 1);
    csr_col[pos] = ei[E + e];
    csr_w[pos]   = ew[e];
  }
}

// ---------------- weight pack: wb[l][n][k2] bf16; k2<128 -> gc_w[l][n][k], else bi_w ----------------
__global__ void pack_wb_kernel(const float* __restrict__ gcw, const float* __restrict__ biw,
                               unsigned short* __restrict__ wb, int LYR){
  int i = blockIdx.x*blockDim.x + threadIdx.x;
  int total = LYR*DD*K2;
  if (i >= total) return;
  int l = i / (DD*K2);
  int r = i - l*(DD*K2);
  int n = r >> 8;        // output col
  int k = r & (K2-1);
  float v = (k < DD) ? gcw[(size_t)l*DD*DD + n*DD + k]
                     : biw[(size_t)l*DD*DD + n*DD + (k - DD)];
  wb[i] = f2bf(v);
}

// ---------------- gather: msg[n] = sum_e w*ego[col]  (one wave per node) ----------------
__global__ void gather_kernel(const int* __restrict__ rowptr, const int* __restrict__ csr_col,
                              const float* __restrict__ csr_w, const float* __restrict__ ego,
                              float* __restrict__ msg, int N){
  int wid = (int)(((size_t)blockIdx.x*blockDim.x + threadIdx.x) >> 6);
  int lane = threadIdx.x & 63;
  if (wid >= N) return;
  int beg = rowptr[wid], end = rowptr[wid+1];
  float ax = 0.f, ay = 0.f;
  for (int k = beg; k < end; k++){
    int c = csr_col[k];
    float w = csr_w[k];
    float2 v = *(const float2*)(ego + (size_t)c*DD + lane*2);
    ax = fmaf(w, v.x, ax);
    ay = fmaf(w, v.y, ay);
  }
  float2* mo = (float2*)(msg + (size_t)wid*DD);
  mo[lane] = make_float2(ax, ay);
}

// ---------------- transform (bf16 MFMA, K=256 concat GEMM) ----------------
// ego_out = leakyrelu([msg | ego*msg] @ [gc_w | bi_w]^T + gcb + bib), fused row-norm scale.
// Block: 128 threads = 2 waves, 64 rows. Wave: 32 rows x 128 cols.
__global__ __launch_bounds__(128) void transform_mfma_kernel(
    const float* __restrict__ ego_in, const float* __restrict__ msg,
    const unsigned short* __restrict__ wb, const float* __restrict__ gcb,
    const float* __restrict__ bib, float* __restrict__ ego_out,
    float* __restrict__ nscale, int N){
  __shared__ unsigned short As[64*264];   // 64 rows x (256 + 8 pad) bf16 = 33 KB
  __shared__ float Bias[DD];
  int t = threadIdx.x;
  int r0 = blockIdx.x * 64;
  if (t < DD) Bias[t] = gcb[t] + bib[t];

  // stage 64 rows x 128 cols of msg/ego (fp32, coalesced float4) -> bf16 LDS tile
#pragma unroll
  for (int it = 0; it < 16; it++){
    int i = it*128 + t;
    int r = i >> 5, c4 = (i & 31)*4;
    int gr = r0 + r;
    float4 m4 = make_float4(0.f,0.f,0.f,0.f);
    float4 e4 = m4;
    if (gr < N){
      m4 = *(const float4*)(msg    + (size_t)gr*DD + c4);
      e4 = *(const float4*)(ego_in + (size_t)gr*DD + c4);
    }
    unsigned int m01 = f2bf(m4.x) | ((unsigned int)f2bf(m4.y) << 16);
    unsigned int m23 = f2bf(m4.z) | ((unsigned int)f2bf(m4.w) << 16);
    unsigned int p01 = f2bf(e4.x*m4.x) | ((unsigned int)f2bf(e4.y*m4.y) << 16);
    unsigned int p23 = f2bf(e4.z*m4.z) | ((unsigned int)f2bf(e4.w*m4.w) << 16);
    *(uint2*)&As[r*264 + c4]       = make_uint2(m01, m23);  // msg half   (k < 128)
    *(uint2*)&As[r*264 + DD + c4]  = make_uint2(p01, p23);  // prod half  (k >= 128)
  }
  __syncthreads();

  int wave = t >> 6, lane = t & 63;
  int m = lane & 15, q = lane >> 4;
  int wr0 = wave * 32;

  f32x4 acc[8][2];
#pragma unroll
  for (int ct = 0; ct < 8; ct++){
    acc[ct][0] = (f32x4)0.f;
    acc[ct][1] = (f32x4)0.f;
  }

#pragma unroll
  for (int kc = 0; kc < 8; kc++){
    int koff = kc*32 + q*8;
    // A frag: A[m][k] = As[row][k], 8 contiguous bf16 (ds_read_b128)
    short8 a0 = *(const short8*)&As[(wr0 + m)*264 + koff];
    short8 a1 = *(const short8*)&As[(wr0 + 16 + m)*264 + koff];
#pragma unroll
    for (int ct = 0; ct < 8; ct++){
      // B frag: B[k][n] = wb[n][k], 8 contiguous bf16 from L2-resident packed weights
      short8 b = *(const short8*)&wb[(size_t)(ct*16 + m)*K2 + koff];
      acc[ct][0] = __builtin_amdgcn_mfma_f32_16x16x32_bf16(a0, b, acc[ct][0], 0, 0, 0);
      acc[ct][1] = __builtin_amdgcn_mfma_f32_16x16x32_bf16(a1, b, acc[ct][1], 0, 0, 0);
    }
  }

  // epilogue: bias + leaky_relu + store + fused row-norm scale
  // C/D layout: col = ct*16 + m, row = wr0 + rt*16 + q*4 + reg
#pragma unroll
  for (int rt = 0; rt < 2; rt++){
#pragma unroll
    for (int reg = 0; reg < 4; reg++){
      int gr = r0 + wr0 + rt*16 + q*4 + reg;
      float rs = 0.f;
#pragma unroll
      for (int ct = 0; ct < 8; ct++){
        float x = acc[ct][rt][reg] + Bias[ct*16 + m];
        x = (x > 0.f) ? x : 0.2f*x;
        rs += x*x;
        if (gr < N) ego_out[(size_t)gr*DD + ct*16 + m] = x;
      }
#pragma unroll
      for (int o = 1; o < 16; o <<= 1) rs += __shfl_xor(rs, o, 16);
      if (m == 0 && gr < N)
        nscale[gr] = 1.0f / fmaxf(sqrtf(rs), 1e-12f);
    }
  }
}

// ---------------- score: out[q] (+)= scale_s*scale_d * dot(feat[s], feat[d]) ----------------
__global__ void score_kernel(const int* __restrict__ eli, int Q,
                             const float* __restrict__ feat, const float* __restrict__ nscale,
                             float* __restrict__ out, int accumulate){
  int wid = (int)(((size_t)blockIdx.x*blockDim.x + threadIdx.x) >> 6);
  int lane = threadIdx.x & 63;
  if (wid >= Q) return;
  int s = eli[wid];
  int d = eli[Q + wid];
  float2 a = *(const float2*)(feat + (size_t)s*DD + lane*2);
  float2 b = *(const float2*)(feat + (size_t)d*DD + lane*2);
  float p = a.x*b.x + a.y*b.y;
  for (int o = 32; o > 0; o >>= 1) p += __shfl_xor(p, o, 64);
  if (lane == 0){
    if (nscale) p *= nscale[s]*nscale[d];
    if (accumulate) out[wid] += p;
    else            out[wid]  = p;
  }
}

extern "C" void kernel_launch(void* const* d_in, const int* in_sizes, int n_in,
                              void* d_out, int out_size, void* d_ws, size_t ws_size,
                              hipStream_t stream){
  const int*   edge_index = (const int*)d_in[0];   // (2,E)
  const int*   eli        = (const int*)d_in[1];   // (2,Q)
  const float* ew         = (const float*)d_in[2]; // (E,)
  const float* emb        = (const float*)d_in[3]; // (N,D)
  const float* gcw        = (const float*)d_in[4]; // (L,D,D)
  const float* gcb        = (const float*)d_in[5]; // (L,D)
  const float* biw        = (const float*)d_in[6]; // (L,D,D)
  const float* bib        = (const float*)d_in[7]; // (L,D)
  const int E   = in_sizes[2];
  const int Q   = in_sizes[1] / 2;
  const int N   = in_sizes[3] / DD;
  const int LYR = in_sizes[4] / (DD*DD);
  float* out = (float*)d_out;

  // workspace carve
  char* base = (char*)d_ws;
  size_t off = 0;
  auto carve = [&](size_t bytes)->char*{
    char* r = base + off;
    off = align256(off + bytes);
    return r;
  };
  float*          ego    = (float*)          carve((size_t)N*DD*sizeof(float));
  float*          msg    = (float*)          carve((size_t)N*DD*sizeof(float));
  unsigned short* wb     = (unsigned short*) carve((size_t)LYR*DD*K2*sizeof(unsigned short));
  float*          nscale = (float*)          carve((size_t)N*sizeof(float));
  int*            rowptr = (int*)            carve((size_t)(N+1)*sizeof(int));
  int*            deg    = (int*)            carve((size_t)2*N*sizeof(int));  // deg + cur
  int*            cur    = deg + N;
  int*            csum   = (int*)            carve(4096);
  int*            csr_col= (int*)            carve((size_t)E*sizeof(int));
  float*          csr_w  = (float*)          carve((size_t)E*sizeof(float));
  (void)ws_size; (void)n_in; (void)out_size;

  const int C = (N + 1023)/1024;

  // CSR build
  zero_i32_kernel<<<(2*N + 255)/256, 256, 0, stream>>>(deg, 2*N);
  degree_kernel<<<(E + 255)/256, 256, 0, stream>>>(edge_index, E, deg);
  chunk_sum_kernel<<<C, 256, 0, stream>>>(deg, N, csum);
  chunk_scan_kernel<<<1, 64, 0, stream>>>(csum, C, rowptr + N);
  scan_within_kernel<<<C, 256, 0, stream>>>(deg, N, csum, rowptr);
  fill_kernel<<<(E + 255)/256, 256, 0, stream>>>(edge_index, ew, E, rowptr, cur, csr_col, csr_w);
  pack_wb_kernel<<<(LYR*DD*K2 + 255)/256, 256, 0, stream>>>(gcw, biw, wb, LYR);

  // stage 0: raw emb dot
  {
    int blocks = (int)(((size_t)Q*64 + 255)/256);
    score_kernel<<<blocks, 256, 0, stream>>>(eli, Q, emb, (const float*)nullptr, out, 0);
  }

  for (int l = 0; l < LYR; l++){
    const float* src = (l == 0) ? emb : ego;
    {
      int blocks = (int)(((size_t)N*64 + 255)/256);
      gather_kernel<<<blocks, 256, 0, stream>>>(rowptr, csr_col, csr_w, src, msg, N);
    }
    transform_mfma_kernel<<<(N + 63)/64, 128, 0, stream>>>(
        src, msg, wb + (size_t)l*DD*K2, gcb + (size_t)l*DD, bib + (size_t)l*DD,
        ego, nscale, N);
    {
      int blocks = (int)(((size_t)Q*64 + 255)/256);
      score_kernel<<<blocks, 256, 0, stream>>>(eli, Q, ego, nscale, out, 1);
    }
  }
}

// Round 3
// 722.547 us; speedup vs baseline: 2.1208x; 1.4981x over previous
//
#include <hip/hip_runtime.h>

#define DD 128
#define K2 256   // concatenated K: [msg | ego*msg]

typedef short short8 __attribute__((ext_vector_type(8)));
typedef float f32x4  __attribute__((ext_vector_type(4)));

static inline size_t align256(size_t x){ return (x + 255) & ~(size_t)255; }

__device__ __forceinline__ unsigned short f2bf(float x){
  unsigned int u = __builtin_bit_cast(unsigned int, x);
  u += 0x7fff + ((u >> 16) & 1);          // RNE fp32 -> bf16
  return (unsigned short)(u >> 16);
}
__device__ __forceinline__ float bf2f(unsigned short h){
  unsigned int u = ((unsigned int)h) << 16;
  return __builtin_bit_cast(float, u);
}

// ---------------- utility ----------------
__global__ void zero_i32_kernel(int* __restrict__ p, int n){
  int i = blockIdx.x*blockDim.x + threadIdx.x;
  if (i < n) p[i] = 0;
}

// emb fp32 -> bf16 (packed 2/uint)
__global__ void cvt_bf16_kernel(const float* __restrict__ src, unsigned int* __restrict__ dst, int n2){
  int i = blockIdx.x*blockDim.x + threadIdx.x;   // one uint = 2 elems
  if (i < n2){
    float2 v = *(const float2*)(src + (size_t)i*2);
    dst[i] = (unsigned int)f2bf(v.x) | ((unsigned int)f2bf(v.y) << 16);
  }
}

// ---------------- CSR build ----------------
__global__ void degree_kernel(const int* __restrict__ row, int E, int* __restrict__ deg){
  int e = blockIdx.x*blockDim.x + threadIdx.x;
  if (e < E) atomicAdd(&deg[row[e]], 1);
}

__global__ void chunk_sum_kernel(const int* __restrict__ deg, int N, int* __restrict__ csum){
  __shared__ int sh[256];
  int t = threadIdx.x;
  int base = blockIdx.x*1024;
  int s = 0;
  for (int i = t; i < 1024; i += 256){
    int idx = base + i;
    if (idx < N) s += deg[idx];
  }
  sh[t] = s; __syncthreads();
  for (int o = 128; o > 0; o >>= 1){
    if (t < o) sh[t] += sh[t+o];
    __syncthreads();
  }
  if (t == 0) csum[blockIdx.x] = sh[0];
}

__global__ void chunk_scan_kernel(int* __restrict__ csum, int C, int* __restrict__ total){
  if (blockIdx.x == 0 && threadIdx.x == 0){
    int run = 0;
    for (int i = 0; i < C; i++){ int v = csum[i]; csum[i] = run; run += v; }
    *total = run;
  }
}

__global__ void scan_within_kernel(const int* __restrict__ deg, int N,
                                   const int* __restrict__ csum, int* __restrict__ rowptr){
  __shared__ int a[256], b[256];
  int t = threadIdx.x;
  int base = blockIdx.x*1024 + t*4;
  int v[4]; int s = 0;
#pragma unroll
  for (int i = 0; i < 4; i++){
    int idx = base + i;
    int d = (idx < N) ? deg[idx] : 0;
    v[i] = s; s += d;
  }
  a[t] = s; __syncthreads();
  int* src = a; int* dst = b;
  for (int o = 1; o < 256; o <<= 1){
    int val = src[t];
    if (t >= o) val += src[t - o];
    dst[t] = val;
    __syncthreads();
    int* tmp = src; src = dst; dst = tmp;
  }
  int excl = (t == 0) ? 0 : src[t-1];
  int off = csum[blockIdx.x] + excl;
#pragma unroll
  for (int i = 0; i < 4; i++){
    int idx = base + i;
    if (idx < N) rowptr[idx] = off + v[i];
  }
}

// packed CSR entry: (col, weight-bits)
__global__ void fill_kernel(const int* __restrict__ ei, const float* __restrict__ ew, int E,
                            const int* __restrict__ rowptr, int* __restrict__ cur,
                            int2* __restrict__ csre){
  int e = blockIdx.x*blockDim.x + threadIdx.x;
  if (e < E){
    int r = ei[e];
    int pos = rowptr[r] + atomicAdd(&cur[r], 1);
    csre[pos] = make_int2(ei[E + e], __float_as_int(ew[e]));
  }
}

// ---------------- weight pack: wb[l][n][k2] bf16; k2<128 -> gc_w[l][n][k], else bi_w ----------------
__global__ void pack_wb_kernel(const float* __restrict__ gcw, const float* __restrict__ biw,
                               unsigned short* __restrict__ wb, int LYR){
  int i = blockIdx.x*blockDim.x + threadIdx.x;
  int total = LYR*DD*K2;
  if (i >= total) return;
  int l = i / (DD*K2);
  int r = i - l*(DD*K2);
  int n = r >> 8;
  int k = r & (K2-1);
  float v = (k < DD) ? gcw[(size_t)l*DD*DD + n*DD + k]
                     : biw[(size_t)l*DD*DD + n*DD + (k - DD)];
  wb[i] = f2bf(v);
}

// ---------------- gather: msgh[n] = bf16( sum_e w*egoh[col] )  (one wave per node) --------
__global__ void gather_kernel(const int* __restrict__ rowptr, const int2* __restrict__ csre,
                              const unsigned short* __restrict__ egoh,
                              unsigned int* __restrict__ msgh, int N){
  int wid = (int)(((size_t)blockIdx.x*blockDim.x + threadIdx.x) >> 6);
  int lane = threadIdx.x & 63;
  if (wid >= N) return;
  int beg = rowptr[wid], end = rowptr[wid+1];
  float ax = 0.f, ay = 0.f;
  int k = beg;
  // unrolled x4: 4 independent row-gathers in flight
  for (; k + 4 <= end; k += 4){
    int2 e0 = csre[k], e1 = csre[k+1], e2 = csre[k+2], e3 = csre[k+3];
    unsigned int v0 = *(const unsigned int*)(egoh + (size_t)e0.x*DD + lane*2);
    unsigned int v1 = *(const unsigned int*)(egoh + (size_t)e1.x*DD + lane*2);
    unsigned int v2 = *(const unsigned int*)(egoh + (size_t)e2.x*DD + lane*2);
    unsigned int v3 = *(const unsigned int*)(egoh + (size_t)e3.x*DD + lane*2);
    float w0 = __int_as_float(e0.y), w1 = __int_as_float(e1.y);
    float w2 = __int_as_float(e2.y), w3 = __int_as_float(e3.y);
    ax = fmaf(w0, bf2f((unsigned short)v0), ax); ay = fmaf(w0, bf2f((unsigned short)(v0>>16)), ay);
    ax = fmaf(w1, bf2f((unsigned short)v1), ax); ay = fmaf(w1, bf2f((unsigned short)(v1>>16)), ay);
    ax = fmaf(w2, bf2f((unsigned short)v2), ax); ay = fmaf(w2, bf2f((unsigned short)(v2>>16)), ay);
    ax = fmaf(w3, bf2f((unsigned short)v3), ax); ay = fmaf(w3, bf2f((unsigned short)(v3>>16)), ay);
  }
  for (; k < end; k++){
    int2 e = csre[k];
    unsigned int v = *(const unsigned int*)(egoh + (size_t)e.x*DD + lane*2);
    float w = __int_as_float(e.y);
    ax = fmaf(w, bf2f((unsigned short)v), ax);
    ay = fmaf(w, bf2f((unsigned short)(v>>16)), ay);
  }
  msgh[(size_t)wid*(DD/2) + lane] = (unsigned int)f2bf(ax) | ((unsigned int)f2bf(ay) << 16);
}

// ---------------- transform (bf16 MFMA, K=256 concat GEMM), all-bf16 I/O ----------------
// egoh_out = bf16(leakyrelu([msg | ego*msg] @ [gc_w | bi_w]^T + b)), nscale from fp32 acc.
__global__ __launch_bounds__(128) void transform_mfma_kernel(
    const unsigned short* __restrict__ egoh_in, const unsigned short* __restrict__ msgh,
    const unsigned short* __restrict__ wb, const float* __restrict__ gcb,
    const float* __restrict__ bib, unsigned short* __restrict__ egoh_out,
    float* __restrict__ nscale, int N){
  __shared__ unsigned short As[64*264];   // 64 rows x (256 + 8 pad) bf16
  __shared__ float Bias[DD];
  int t = threadIdx.x;
  int r0 = blockIdx.x * 64;
  if (t < DD) Bias[t] = gcb[t] + bib[t];

  // stage 64 rows: msg half copied, prod half = bf16(ego*msg); uint4 = 8 bf16
#pragma unroll
  for (int it = 0; it < 8; it++){
    int i = it*128 + t;
    int r = i >> 4, c = (i & 15);        // c: uint4 index within row (16 per row)
    int gr = r0 + r;
    uint4 m4 = make_uint4(0,0,0,0), e4 = make_uint4(0,0,0,0);
    if (gr < N){
      m4 = *(const uint4*)(msgh    + (size_t)gr*DD + c*8);
      e4 = *(const uint4*)(egoh_in + (size_t)gr*DD + c*8);
    }
    *(uint4*)&As[r*264 + c*8] = m4;      // msg half (k < 128)
    unsigned int p[4];
    unsigned int me[4] = {m4.x, m4.y, m4.z, m4.w};
    unsigned int ee[4] = {e4.x, e4.y, e4.z, e4.w};
#pragma unroll
    for (int u = 0; u < 4; u++){
      float px = bf2f((unsigned short)me[u]) * bf2f((unsigned short)ee[u]);
      float py = bf2f((unsigned short)(me[u]>>16)) * bf2f((unsigned short)(ee[u]>>16));
      p[u] = (unsigned int)f2bf(px) | ((unsigned int)f2bf(py) << 16);
    }
    *(uint4*)&As[r*264 + DD + c*8] = make_uint4(p[0],p[1],p[2],p[3]);
  }
  __syncthreads();

  int wave = t >> 6, lane = t & 63;
  int m = lane & 15, q = lane >> 4;
  int wr0 = wave * 32;

  f32x4 acc[8][2];
#pragma unroll
  for (int ct = 0; ct < 8; ct++){ acc[ct][0] = (f32x4)0.f; acc[ct][1] = (f32x4)0.f; }

#pragma unroll
  for (int kc = 0; kc < 8; kc++){
    int koff = kc*32 + q*8;
    short8 a0 = *(const short8*)&As[(wr0 + m)*264 + koff];
    short8 a1 = *(const short8*)&As[(wr0 + 16 + m)*264 + koff];
#pragma unroll
    for (int ct = 0; ct < 8; ct++){
      short8 b = *(const short8*)&wb[(size_t)(ct*16 + m)*K2 + koff];
      acc[ct][0] = __builtin_amdgcn_mfma_f32_16x16x32_bf16(a0, b, acc[ct][0], 0, 0, 0);
      acc[ct][1] = __builtin_amdgcn_mfma_f32_16x16x32_bf16(a1, b, acc[ct][1], 0, 0, 0);
    }
  }

  // epilogue: bias + leaky_relu + bf16 store + fused row-norm scale (fp32)
#pragma unroll
  for (int rt = 0; rt < 2; rt++){
#pragma unroll
    for (int reg = 0; reg < 4; reg++){
      int gr = r0 + wr0 + rt*16 + q*4 + reg;
      float rs = 0.f;
#pragma unroll
      for (int ct = 0; ct < 8; ct++){
        float x = acc[ct][rt][reg] + Bias[ct*16 + m];
        x = (x > 0.f) ? x : 0.2f*x;
        rs += x*x;
        if (gr < N) egoh_out[(size_t)gr*DD + ct*16 + m] = f2bf(x);
      }
#pragma unroll
      for (int o = 1; o < 16; o <<= 1) rs += __shfl_xor(rs, o, 16);
      if (m == 0 && gr < N)
        nscale[gr] = 1.0f / fmaxf(sqrtf(rs), 1e-12f);
    }
  }
}

// ---------------- score: out[q] (+)= scale_s*scale_d * dot(feat[s], feat[d]) ----------------
__global__ void score_kernel(const int* __restrict__ eli, int Q,
                             const unsigned short* __restrict__ feath,
                             const float* __restrict__ nscale,
                             float* __restrict__ out, int accumulate){
  int wid = (int)(((size_t)blockIdx.x*blockDim.x + threadIdx.x) >> 6);
  int lane = threadIdx.x & 63;
  if (wid >= Q) return;
  int s = eli[wid];
  int d = eli[Q + wid];
  unsigned int a = *(const unsigned int*)(feath + (size_t)s*DD + lane*2);
  unsigned int b = *(const unsigned int*)(feath + (size_t)d*DD + lane*2);
  float p = bf2f((unsigned short)a)*bf2f((unsigned short)b)
          + bf2f((unsigned short)(a>>16))*bf2f((unsigned short)(b>>16));
  for (int o = 32; o > 0; o >>= 1) p += __shfl_xor(p, o, 64);
  if (lane == 0){
    if (nscale) p *= nscale[s]*nscale[d];
    if (accumulate) out[wid] += p;
    else            out[wid]  = p;
  }
}

extern "C" void kernel_launch(void* const* d_in, const int* in_sizes, int n_in,
                              void* d_out, int out_size, void* d_ws, size_t ws_size,
                              hipStream_t stream){
  const int*   edge_index = (const int*)d_in[0];   // (2,E)
  const int*   eli        = (const int*)d_in[1];   // (2,Q)
  const float* ew         = (const float*)d_in[2]; // (E,)
  const float* emb        = (const float*)d_in[3]; // (N,D)
  const float* gcw        = (const float*)d_in[4]; // (L,D,D)
  const float* gcb        = (const float*)d_in[5]; // (L,D)
  const float* biw        = (const float*)d_in[6]; // (L,D,D)
  const float* bib        = (const float*)d_in[7]; // (L,D)
  const int E   = in_sizes[2];
  const int Q   = in_sizes[1] / 2;
  const int N   = in_sizes[3] / DD;
  const int LYR = in_sizes[4] / (DD*DD);
  float* out = (float*)d_out;

  // workspace carve
  char* base = (char*)d_ws;
  size_t off = 0;
  auto carve = [&](size_t bytes)->char*{
    char* r = base + off;
    off = align256(off + bytes);
    return r;
  };
  unsigned short* embh   = (unsigned short*) carve((size_t)N*DD*sizeof(unsigned short));
  unsigned short* egoh   = (unsigned short*) carve((size_t)N*DD*sizeof(unsigned short));
  unsigned short* msgh   = (unsigned short*) carve((size_t)N*DD*sizeof(unsigned short));
  unsigned short* wb     = (unsigned short*) carve((size_t)LYR*DD*K2*sizeof(unsigned short));
  float*          nscale = (float*)          carve((size_t)N*sizeof(float));
  int*            rowptr = (int*)            carve((size_t)(N+1)*sizeof(int));
  int*            deg    = (int*)            carve((size_t)2*N*sizeof(int));  // deg + cur
  int*            cur    = deg + N;
  int*            csum   = (int*)            carve(4096);
  int2*           csre   = (int2*)           carve((size_t)E*sizeof(int2));
  (void)ws_size; (void)n_in; (void)out_size;

  const int C = (N + 1023)/1024;

  // CSR build + packs
  zero_i32_kernel<<<(2*N + 255)/256, 256, 0, stream>>>(deg, 2*N);
  degree_kernel<<<(E + 255)/256, 256, 0, stream>>>(edge_index, E, deg);
  chunk_sum_kernel<<<C, 256, 0, stream>>>(deg, N, csum);
  chunk_scan_kernel<<<1, 64, 0, stream>>>(csum, C, rowptr + N);
  scan_within_kernel<<<C, 256, 0, stream>>>(deg, N, csum, rowptr);
  fill_kernel<<<(E + 255)/256, 256, 0, stream>>>(edge_index, ew, E, rowptr, cur, csre);
  pack_wb_kernel<<<(LYR*DD*K2 + 255)/256, 256, 0, stream>>>(gcw, biw, wb, LYR);
  cvt_bf16_kernel<<<((N*DD/2) + 255)/256, 256, 0, stream>>>(emb, (unsigned int*)embh, N*DD/2);

  // stage 0: raw emb dot (bf16 copy)
  {
    int blocks = (int)(((size_t)Q*64 + 255)/256);
    score_kernel<<<blocks, 256, 0, stream>>>(eli, Q, embh, (const float*)nullptr, out, 0);
  }

  for (int l = 0; l < LYR; l++){
    const unsigned short* src = (l == 0) ? embh : egoh;
    {
      int blocks = (int)(((size_t)N*64 + 255)/256);
      gather_kernel<<<blocks, 256, 0, stream>>>(rowptr, csre, src, (unsigned int*)msgh, N);
    }
    transform_mfma_kernel<<<(N + 63)/64, 128, 0, stream>>>(
        src, msgh, wb + (size_t)l*DD*K2, gcb + (size_t)l*DD, bib + (size_t)l*DD,
        egoh, nscale, N);
    {
      int blocks = (int)(((size_t)Q*64 + 255)/256);
      score_kernel<<<blocks, 256, 0, stream>>>(eli, Q, egoh, nscale, out, 1);
    }
  }
}

// Round 4
// 703.631 us; speedup vs baseline: 2.1778x; 1.0269x over previous
//
#include <hip/hip_runtime.h>

#define DD 128
#define K2 256     // concatenated K: [msg | ego*msg]
#define NBMAX 1024 // max bucket count (N/128)
#define COLMASK 0x01FFFFFF

typedef short short8 __attribute__((ext_vector_type(8)));
typedef float f32x4  __attribute__((ext_vector_type(4)));

static inline size_t align256(size_t x){ return (x + 255) & ~(size_t)255; }

__device__ __forceinline__ unsigned short f2bf(float x){
  unsigned int u = __builtin_bit_cast(unsigned int, x);
  u += 0x7fff + ((u >> 16) & 1);          // RNE fp32 -> bf16
  return (unsigned short)(u >> 16);
}
__device__ __forceinline__ float bf2f(unsigned short h){
  unsigned int u = ((unsigned int)h) << 16;
  return __builtin_bit_cast(float, u);
}

// ---------------- utility ----------------
__global__ void zero_i32_kernel(int* __restrict__ p, int n){
  int i = blockIdx.x*blockDim.x + threadIdx.x;
  if (i < n) p[i] = 0;
}

// emb fp32 -> bf16 (packed 2/uint)
__global__ void cvt_bf16_kernel(const float* __restrict__ src, unsigned int* __restrict__ dst, int n2){
  int i = blockIdx.x*blockDim.x + threadIdx.x;
  if (i < n2){
    float2 v = *(const float2*)(src + (size_t)i*2);
    dst[i] = (unsigned int)f2bf(v.x) | ((unsigned int)f2bf(v.y) << 16);
  }
}

// ---------------- CSR build: degree + rowptr scan ----------------
__global__ void degree_kernel(const int* __restrict__ row, int E, int* __restrict__ deg){
  int e = blockIdx.x*blockDim.x + threadIdx.x;
  if (e < E) atomicAdd(&deg[row[e]], 1);
}

__global__ void chunk_sum_kernel(const int* __restrict__ deg, int N, int* __restrict__ csum){
  __shared__ int sh[256];
  int t = threadIdx.x;
  int base = blockIdx.x*1024;
  int s = 0;
  for (int i = t; i < 1024; i += 256){
    int idx = base + i;
    if (idx < N) s += deg[idx];
  }
  sh[t] = s; __syncthreads();
  for (int o = 128; o > 0; o >>= 1){
    if (t < o) sh[t] += sh[t+o];
    __syncthreads();
  }
  if (t == 0) csum[blockIdx.x] = sh[0];
}

__global__ void chunk_scan_kernel(int* __restrict__ csum, int C, int* __restrict__ total){
  if (blockIdx.x == 0 && threadIdx.x == 0){
    int run = 0;
    for (int i = 0; i < C; i++){ int v = csum[i]; csum[i] = run; run += v; }
    *total = run;
  }
}

__global__ void scan_within_kernel(const int* __restrict__ deg, int N,
                                   const int* __restrict__ csum, int* __restrict__ rowptr){
  __shared__ int a[256], b[256];
  int t = threadIdx.x;
  int base = blockIdx.x*1024 + t*4;
  int v[4]; int s = 0;
#pragma unroll
  for (int i = 0; i < 4; i++){
    int idx = base + i;
    int d = (idx < N) ? deg[idx] : 0;
    v[i] = s; s += d;
  }
  a[t] = s; __syncthreads();
  int* src = a; int* dst = b;
  for (int o = 1; o < 256; o <<= 1){
    int val = src[t];
    if (t >= o) val += src[t - o];
    dst[t] = val;
    __syncthreads();
    int* tmp = src; src = dst; dst = tmp;
  }
  int excl = (t == 0) ? 0 : src[t-1];
  int off = csum[blockIdx.x] + excl;
#pragma unroll
  for (int i = 0; i < 4; i++){
    int idx = base + i;
    if (idx < N) rowptr[idx] = off + v[i];
  }
}

// ---------------- binned fill, phase A: append into bucket regions ----------------
__global__ void bcur_init_kernel(const int* __restrict__ rowptr, int* __restrict__ bcur,
                                 int NB, int N){
  int b = blockIdx.x*blockDim.x + threadIdx.x;
  if (b < NB){
    int rr = b*128; if (rr > N) rr = N;
    bcur[b] = rowptr[rr];
  }
}

__global__ __launch_bounds__(256) void fill_binned_kernel(
    const int* __restrict__ ei, const float* __restrict__ ew, int E,
    int* __restrict__ bcur, int2* __restrict__ csre, int NB){
  __shared__ int lhist[NBMAX];
  __shared__ int lbase[NBMAX];
  int t = threadIdx.x;
  int base = blockIdx.x * 4096;
  for (int j = t; j < NB; j += 256) lhist[j] = 0;
  __syncthreads();
  int rows[16];
#pragma unroll
  for (int i = 0; i < 16; i++){
    int e = base + i*256 + t;
    int r = (e < E) ? ei[e] : -1;
    rows[i] = r;
    if (r >= 0) atomicAdd(&lhist[r >> 7], 1);
  }
  __syncthreads();
  for (int j = t; j < NB; j += 256){
    int c = lhist[j];
    lbase[j] = c ? atomicAdd(&bcur[j], c) : 0;
    lhist[j] = 0;                     // reuse as local cursor
  }
  __syncthreads();
#pragma unroll
  for (int i = 0; i < 16; i++){
    int e = base + i*256 + t;
    int r = rows[i];
    if (r >= 0){
      int b = r >> 7;
      int pos = lbase[b] + atomicAdd(&lhist[b], 1);
      int col = ei[E + e];
      float w = ew[e];
      csre[pos] = make_int2(((r & 127) << 25) | col, __float_as_int(w));
    }
  }
}

// ---------------- binned fill, phase B: rank by row within bucket -> exact CSR ----------------
__global__ __launch_bounds__(256) void sortbkt_kernel(
    const int* __restrict__ rowptr, const int2* __restrict__ csre,
    int2* __restrict__ csre2, int N){
  __shared__ int lrp[129];
  __shared__ int lcur[128];
  int b = blockIdx.x;
  int t = threadIdx.x;
  int r0 = b*128;
  for (int j = t; j < 129; j += 256){
    int rr = r0 + j; if (rr > N) rr = N;
    lrp[j] = rowptr[rr];
  }
  if (t < 128) lcur[t] = 0;
  __syncthreads();
  int beg = lrp[0], end = lrp[128];
  for (int i = beg + t; i < end; i += 256){
    int2 e = csre[i];
    int rl = ((unsigned int)e.x) >> 25;
    int pos = lrp[rl] + atomicAdd(&lcur[rl], 1);
    csre2[pos] = e;                   // scattered only within ~16 KB window
  }
}

// ---------------- weight pack: wb[l][n][k2] bf16 ----------------
__global__ void pack_wb_kernel(const float* __restrict__ gcw, const float* __restrict__ biw,
                               unsigned short* __restrict__ wb, int LYR){
  int i = blockIdx.x*blockDim.x + threadIdx.x;
  int total = LYR*DD*K2;
  if (i >= total) return;
  int l = i / (DD*K2);
  int r = i - l*(DD*K2);
  int n = r >> 8;
  int k = r & (K2-1);
  float v = (k < DD) ? gcw[(size_t)l*DD*DD + n*DD + k]
                     : biw[(size_t)l*DD*DD + n*DD + (k - DD)];
  wb[i] = f2bf(v);
}

// ---------------- gather: msgh[n] = bf16( sum_e w*egoh[col] )  (one wave per node) --------
__global__ void gather_kernel(const int* __restrict__ rowptr, const int2* __restrict__ csre,
                              const unsigned short* __restrict__ egoh,
                              unsigned int* __restrict__ msgh, int N){
  int wid = (int)(((size_t)blockIdx.x*blockDim.x + threadIdx.x) >> 6);
  int lane = threadIdx.x & 63;
  if (wid >= N) return;
  int beg = rowptr[wid], end = rowptr[wid+1];
  float ax = 0.f, ay = 0.f;
  int k = beg;
  // unrolled x8: 8 independent row-gathers in flight
  for (; k + 8 <= end; k += 8){
    int2 e[8]; unsigned int v[8];
#pragma unroll
    for (int u = 0; u < 8; u++) e[u] = csre[k+u];
#pragma unroll
    for (int u = 0; u < 8; u++)
      v[u] = *(const unsigned int*)(egoh + (size_t)(e[u].x & COLMASK)*DD + lane*2);
#pragma unroll
    for (int u = 0; u < 8; u++){
      float w = __int_as_float(e[u].y);
      ax = fmaf(w, bf2f((unsigned short)v[u]), ax);
      ay = fmaf(w, bf2f((unsigned short)(v[u]>>16)), ay);
    }
  }
  for (; k < end; k++){
    int2 e = csre[k];
    unsigned int v = *(const unsigned int*)(egoh + (size_t)(e.x & COLMASK)*DD + lane*2);
    float w = __int_as_float(e.y);
    ax = fmaf(w, bf2f((unsigned short)v), ax);
    ay = fmaf(w, bf2f((unsigned short)(v>>16)), ay);
  }
  msgh[(size_t)wid*(DD/2) + lane] = (unsigned int)f2bf(ax) | ((unsigned int)f2bf(ay) << 16);
}

// ---------------- transform (bf16 MFMA, K=256 concat GEMM), all-bf16 I/O ----------------
__global__ __launch_bounds__(128) void transform_mfma_kernel(
    const unsigned short* __restrict__ egoh_in, const unsigned short* __restrict__ msgh,
    const unsigned short* __restrict__ wb, const float* __restrict__ gcb,
    const float* __restrict__ bib, unsigned short* __restrict__ egoh_out,
    float* __restrict__ nscale, int N){
  __shared__ unsigned short As[64*264];
  __shared__ float Bias[DD];
  int t = threadIdx.x;
  int r0 = blockIdx.x * 64;
  if (t < DD) Bias[t] = gcb[t] + bib[t];

#pragma unroll
  for (int it = 0; it < 8; it++){
    int i = it*128 + t;
    int r = i >> 4, c = (i & 15);
    int gr = r0 + r;
    uint4 m4 = make_uint4(0,0,0,0), e4 = make_uint4(0,0,0,0);
    if (gr < N){
      m4 = *(const uint4*)(msgh    + (size_t)gr*DD + c*8);
      e4 = *(const uint4*)(egoh_in + (size_t)gr*DD + c*8);
    }
    *(uint4*)&As[r*264 + c*8] = m4;
    unsigned int p[4];
    unsigned int me[4] = {m4.x, m4.y, m4.z, m4.w};
    unsigned int ee[4] = {e4.x, e4.y, e4.z, e4.w};
#pragma unroll
    for (int u = 0; u < 4; u++){
      float px = bf2f((unsigned short)me[u]) * bf2f((unsigned short)ee[u]);
      float py = bf2f((unsigned short)(me[u]>>16)) * bf2f((unsigned short)(ee[u]>>16));
      p[u] = (unsigned int)f2bf(px) | ((unsigned int)f2bf(py) << 16);
    }
    *(uint4*)&As[r*264 + DD + c*8] = make_uint4(p[0],p[1],p[2],p[3]);
  }
  __syncthreads();

  int wave = t >> 6, lane = t & 63;
  int m = lane & 15, q = lane >> 4;
  int wr0 = wave * 32;

  f32x4 acc[8][2];
#pragma unroll
  for (int ct = 0; ct < 8; ct++){ acc[ct][0] = (f32x4)0.f; acc[ct][1] = (f32x4)0.f; }

#pragma unroll
  for (int kc = 0; kc < 8; kc++){
    int koff = kc*32 + q*8;
    short8 a0 = *(const short8*)&As[(wr0 + m)*264 + koff];
    short8 a1 = *(const short8*)&As[(wr0 + 16 + m)*264 + koff];
#pragma unroll
    for (int ct = 0; ct < 8; ct++){
      short8 b = *(const short8*)&wb[(size_t)(ct*16 + m)*K2 + koff];
      acc[ct][0] = __builtin_amdgcn_mfma_f32_16x16x32_bf16(a0, b, acc[ct][0], 0, 0, 0);
      acc[ct][1] = __builtin_amdgcn_mfma_f32_16x16x32_bf16(a1, b, acc[ct][1], 0, 0, 0);
    }
  }

#pragma unroll
  for (int rt = 0; rt < 2; rt++){
#pragma unroll
    for (int reg = 0; reg < 4; reg++){
      int gr = r0 + wr0 + rt*16 + q*4 + reg;
      float rs = 0.f;
#pragma unroll
      for (int ct = 0; ct < 8; ct++){
        float x = acc[ct][rt][reg] + Bias[ct*16 + m];
        x = (x > 0.f) ? x : 0.2f*x;
        rs += x*x;
        if (gr < N) egoh_out[(size_t)gr*DD + ct*16 + m] = f2bf(x);
      }
#pragma unroll
      for (int o = 1; o < 16; o <<= 1) rs += __shfl_xor(rs, o, 16);
      if (m == 0 && gr < N)
        nscale[gr] = 1.0f / fmaxf(sqrtf(rs), 1e-12f);
    }
  }
}

// ---------------- score ----------------
__global__ void score_kernel(const int* __restrict__ eli, int Q,
                             const unsigned short* __restrict__ feath,
                             const float* __restrict__ nscale,
                             float* __restrict__ out, int accumulate){
  int wid = (int)(((size_t)blockIdx.x*blockDim.x + threadIdx.x) >> 6);
  int lane = threadIdx.x & 63;
  if (wid >= Q) return;
  int s = eli[wid];
  int d = eli[Q + wid];
  unsigned int a = *(const unsigned int*)(feath + (size_t)s*DD + lane*2);
  unsigned int b = *(const unsigned int*)(feath + (size_t)d*DD + lane*2);
  float p = bf2f((unsigned short)a)*bf2f((unsigned short)b)
          + bf2f((unsigned short)(a>>16))*bf2f((unsigned short)(b>>16));
  for (int o = 32; o > 0; o >>= 1) p += __shfl_xor(p, o, 64);
  if (lane == 0){
    if (nscale) p *= nscale[s]*nscale[d];
    if (accumulate) out[wid] += p;
    else            out[wid]  = p;
  }
}

extern "C" void kernel_launch(void* const* d_in, const int* in_sizes, int n_in,
                              void* d_out, int out_size, void* d_ws, size_t ws_size,
                              hipStream_t stream){
  const int*   edge_index = (const int*)d_in[0];
  const int*   eli        = (const int*)d_in[1];
  const float* ew         = (const float*)d_in[2];
  const float* emb        = (const float*)d_in[3];
  const float* gcw        = (const float*)d_in[4];
  const float* gcb        = (const float*)d_in[5];
  const float* biw        = (const float*)d_in[6];
  const float* bib        = (const float*)d_in[7];
  const int E   = in_sizes[2];
  const int Q   = in_sizes[1] / 2;
  const int N   = in_sizes[3] / DD;
  const int LYR = in_sizes[4] / (DD*DD);
  float* out = (float*)d_out;

  char* base = (char*)d_ws;
  size_t off = 0;
  auto carve = [&](size_t bytes)->char*{
    char* r = base + off;
    off = align256(off + bytes);
    return r;
  };
  unsigned short* embh   = (unsigned short*) carve((size_t)N*DD*sizeof(unsigned short));
  unsigned short* egoh   = (unsigned short*) carve((size_t)N*DD*sizeof(unsigned short));
  unsigned short* msgh   = (unsigned short*) carve((size_t)N*DD*sizeof(unsigned short));
  unsigned short* wb     = (unsigned short*) carve((size_t)LYR*DD*K2*sizeof(unsigned short));
  float*          nscale = (float*)          carve((size_t)N*sizeof(float));
  int*            rowptr = (int*)            carve((size_t)(N+1)*sizeof(int));
  int*            deg    = (int*)            carve((size_t)N*sizeof(int));
  int*            bcur   = (int*)            carve((size_t)NBMAX*sizeof(int));
  int*            csum   = (int*)            carve(4096);
  int2*           csre   = (int2*)           carve((size_t)E*sizeof(int2));
  int2*           csre2  = (int2*)           carve((size_t)E*sizeof(int2));
  (void)ws_size; (void)n_in; (void)out_size;

  const int C  = (N + 1023)/1024;
  const int NB = (N + 127)/128;

  // CSR build (rowptr) + binned fill + packs
  zero_i32_kernel<<<(N + 255)/256, 256, 0, stream>>>(deg, N);
  degree_kernel<<<(E + 255)/256, 256, 0, stream>>>(edge_index, E, deg);
  chunk_sum_kernel<<<C, 256, 0, stream>>>(deg, N, csum);
  chunk_scan_kernel<<<1, 64, 0, stream>>>(csum, C, rowptr + N);
  scan_within_kernel<<<C, 256, 0, stream>>>(deg, N, csum, rowptr);
  bcur_init_kernel<<<(NB + 255)/256, 256, 0, stream>>>(rowptr, bcur, NB, N);
  fill_binned_kernel<<<(E + 4095)/4096, 256, 0, stream>>>(edge_index, ew, E, bcur, csre, NB);
  sortbkt_kernel<<<NB, 256, 0, stream>>>(rowptr, csre, csre2, N);
  pack_wb_kernel<<<(LYR*DD*K2 + 255)/256, 256, 0, stream>>>(gcw, biw, wb, LYR);
  cvt_bf16_kernel<<<((N*DD/2) + 255)/256, 256, 0, stream>>>(emb, (unsigned int*)embh, N*DD/2);

  // stage 0: raw emb dot (bf16 copy)
  {
    int blocks = (int)(((size_t)Q*64 + 255)/256);
    score_kernel<<<blocks, 256, 0, stream>>>(eli, Q, embh, (const float*)nullptr, out, 0);
  }

  for (int l = 0; l < LYR; l++){
    const unsigned short* src = (l == 0) ? embh : egoh;
    {
      int blocks = (int)(((size_t)N*64 + 255)/256);
      gather_kernel<<<blocks, 256, 0, stream>>>(rowptr, csre2, src, (unsigned int*)msgh, N);
    }
    transform_mfma_kernel<<<(N + 63)/64, 128, 0, stream>>>(
        src, msgh, wb + (size_t)l*DD*K2, gcb + (size_t)l*DD, bib + (size_t)l*DD,
        egoh, nscale, N);
    {
      int blocks = (int)(((size_t)Q*64 + 255)/256);
      score_kernel<<<blocks, 256, 0, stream>>>(eli, Q, egoh, nscale, out, 1);
    }
  }
}